// Round 2
// baseline (747.765 us; speedup 1.0000x reference)
//
#include <hip/hip_runtime.h>
#include <hip/hip_bf16.h>

// Problem: N=4, S=4096, E=1024, H=16, D=64.
// Reference = "attention over heads": per (n,s) position, 16x16 softmax across
// heads over head-dim dots, then scrambled (N,H,S,D)->(N,S,E) reshape + output
// projection. Pipeline:
//   K0: detect input dtype (bf16 vs fp32) -> flag in ws
//   K1: QKV projections (3x GEMM 16384x1024x1024 NT +bias) -> ws (Q,K,V natural)
//   K2: per-position head-attention, written IN-PLACE into Qb (natural layout)
//   K3: output projection; scrambled-reshape folded into A-staging addresses
// Internal math: bf16 MFMA (plain for bf16 inputs; split hi/lo x3 for fp32
// inputs so error vs fp32 ref is ~1e-4). fp32 accumulate everywhere.

#include <stddef.h>

typedef __bf16 bf16_t;
typedef __bf16 bf16x8 __attribute__((ext_vector_type(8)));
typedef float  f32x4  __attribute__((ext_vector_type(4)));

static constexpr int Sdim = 4096;
static constexpr int Edim = 1024;
static constexpr int Mrows = 4 * Sdim;                 // 16384
static constexpr size_t MATEL = (size_t)Mrows * Edim;  // 16.7M elems
static constexpr int BM = 128, BN = 128, BK = 32;
static constexpr int TILE = BM * BK;

// ---------------- dtype detection ----------------
// For bf16 tensors, u16[2*i] is a clean bf16 (exponent near 126 for x~N(0,1)).
// For fp32 tensors, u16[2*i] is the low mantissa half: ~uniform bits, only
// ~16% land in the plausible-exponent band. Threshold at 50%.
__global__ void detect_dtype_kernel(const unsigned short* __restrict__ xu,
                                    int* __restrict__ flag) {
  __shared__ int sh[256];
  const int t = threadIdx.x;
  int cnt = 0;
  for (int i = t; i < 1024; i += 256) {
    const unsigned short u = xu[2 * i];
    const int e = (u >> 7) & 0xFF;
    cnt += (e >= 100 && e <= 145) ? 1 : 0;
  }
  sh[t] = cnt;
  __syncthreads();
  for (int s = 128; s > 0; s >>= 1) {
    if (t < s) sh[t] += sh[t + s];
    __syncthreads();
  }
  if (t == 0) flag[0] = (sh[0] >= 512) ? 1 : 0;  // 1 = bf16, 0 = fp32
}

// ---------------- GEMM core ----------------
// C[m,n] = sum_k A[m,k]*B[n,k] + bias[n].  B always natural NT (row n has K
// contiguous). SCRA: A is the attention output in NATURAL (pos, h*64+d)
// layout, accessed through the scrambled-reshape permutation:
//   scrambled row R = n*4096 + h*256 + s_hi, col c = s_lo*64 + d
//   -> natural row n*4096 + s_hi*16 + s_lo, col h*64 + d
template <typename TIn, bool SCRA>
__device__ __forceinline__ void gemm_core(const TIn* __restrict__ A,
                                          const TIn* __restrict__ B,
                                          const TIn* __restrict__ bias,
                                          TIn* __restrict__ C) {
  constexpr bool F32 = (sizeof(TIn) == 4);
  __shared__ __align__(16) bf16_t As[(F32 ? 2 : 1) * TILE];
  __shared__ __align__(16) bf16_t Bs[(F32 ? 2 : 1) * TILE];
  const int t = threadIdx.x;
  const int bm = blockIdx.x * BM;
  const int bn = blockIdx.y * BN;
  const int lane = t & 63;
  const int wave = t >> 6;
  const int wm = (wave >> 1) * 64;  // 2x2 waves of 64x64
  const int wn = (wave & 1) * 64;
  const int row16 = lane & 15;
  const int quad = lane >> 4;

  f32x4 acc[4][4] = {};

  const int lr = t >> 2;        // staging row 0..63 (plus +64 on second half)
  const int lc = (t & 3) * 8;   // col offset within BK tile: 0,8,16,24

  for (int k0 = 0; k0 < Edim; k0 += BK) {
#pragma unroll
    for (int half = 0; half < 2; half++) {
      const int r = lr + half * 64;
      const TIn* ga;
      if constexpr (SCRA) {
        const int R = bm + r;
        const int n = R >> 12, h = (R >> 8) & 15, shi = R & 255;
        const int c = k0 + lc;  // 8-elem chunk stays inside one 64-col block
        ga = A + ((size_t)((n << 12) + (shi << 4) + (c >> 6))) * Edim +
             (h << 6) + (c & 63);
      } else {
        ga = A + (size_t)(bm + r) * Edim + k0 + lc;
      }
      const TIn* gb = B + (size_t)(bn + r) * Edim + k0 + lc;
      const int di = r * BK + lc;
      if constexpr (F32) {
        const f32x4 a0 = *(const f32x4*)ga;
        const f32x4 a1 = *(const f32x4*)(ga + 4);
        const f32x4 b0 = *(const f32x4*)gb;
        const f32x4 b1 = *(const f32x4*)(gb + 4);
        bf16x8 ah, al, bh, bl;
#pragma unroll
        for (int j = 0; j < 4; j++) {
          const float va = a0[j]; const bf16_t h0 = (bf16_t)va;
          ah[j] = h0; al[j] = (bf16_t)(va - (float)h0);
          const float vb = a1[j]; const bf16_t h1 = (bf16_t)vb;
          ah[4 + j] = h1; al[4 + j] = (bf16_t)(vb - (float)h1);
          const float wa = b0[j]; const bf16_t h2 = (bf16_t)wa;
          bh[j] = h2; bl[j] = (bf16_t)(wa - (float)h2);
          const float wb = b1[j]; const bf16_t h3 = (bf16_t)wb;
          bh[4 + j] = h3; bl[4 + j] = (bf16_t)(wb - (float)h3);
        }
        *(bf16x8*)&As[di] = ah; *(bf16x8*)&As[TILE + di] = al;
        *(bf16x8*)&Bs[di] = bh; *(bf16x8*)&Bs[TILE + di] = bl;
      } else {
        *(bf16x8*)&As[di] = *(const bf16x8*)ga;
        *(bf16x8*)&Bs[di] = *(const bf16x8*)gb;
      }
    }
    __syncthreads();

    bf16x8 afh[4], bfh[4];
#pragma unroll
    for (int i = 0; i < 4; i++)
      afh[i] = *(const bf16x8*)&As[(wm + i * 16 + row16) * BK + quad * 8];
#pragma unroll
    for (int j = 0; j < 4; j++)
      bfh[j] = *(const bf16x8*)&Bs[(wn + j * 16 + row16) * BK + quad * 8];

    if constexpr (F32) {
      bf16x8 afl[4], bfl[4];
#pragma unroll
      for (int i = 0; i < 4; i++)
        afl[i] = *(const bf16x8*)&As[TILE + (wm + i * 16 + row16) * BK + quad * 8];
#pragma unroll
      for (int j = 0; j < 4; j++)
        bfl[j] = *(const bf16x8*)&Bs[TILE + (wn + j * 16 + row16) * BK + quad * 8];
#pragma unroll
      for (int i = 0; i < 4; i++)
#pragma unroll
        for (int j = 0; j < 4; j++) {
          acc[i][j] = __builtin_amdgcn_mfma_f32_16x16x32_bf16(afh[i], bfh[j], acc[i][j], 0, 0, 0);
          acc[i][j] = __builtin_amdgcn_mfma_f32_16x16x32_bf16(afh[i], bfl[j], acc[i][j], 0, 0, 0);
          acc[i][j] = __builtin_amdgcn_mfma_f32_16x16x32_bf16(afl[i], bfh[j], acc[i][j], 0, 0, 0);
        }
    } else {
#pragma unroll
      for (int i = 0; i < 4; i++)
#pragma unroll
        for (int j = 0; j < 4; j++)
          acc[i][j] = __builtin_amdgcn_mfma_f32_16x16x32_bf16(afh[i], bfh[j], acc[i][j], 0, 0, 0);
    }
    __syncthreads();
  }

  // Epilogue. C/D layout: col = lane&15, row = quad*4 + reg  [m89-verified]
#pragma unroll
  for (int j = 0; j < 4; j++) {
    const int col = bn + wn + j * 16 + row16;
    const float bv = (float)bias[col];
#pragma unroll
    for (int i = 0; i < 4; i++) {
      const int rb = bm + wm + i * 16 + quad * 4;
#pragma unroll
      for (int r = 0; r < 4; r++)
        C[(size_t)(rb + r) * Edim + col] = (TIn)(acc[i][j][r] + bv);
    }
  }
}

// ---------------- kernels (dtype-guarded) ----------------
template <typename TIn, int WANT>
__global__ __launch_bounds__(256) void qkv_kernel(
    const int* __restrict__ flag, const TIn* __restrict__ x,
    const TIn* __restrict__ Wq, const TIn* __restrict__ bq,
    const TIn* __restrict__ Wk, const TIn* __restrict__ bk,
    const TIn* __restrict__ Wv, const TIn* __restrict__ bv,
    char* __restrict__ wsb) {
  if (*flag != WANT) return;
  TIn* Qb = (TIn*)wsb;
  TIn* Kb = Qb + MATEL;
  TIn* Vb = Kb + MATEL;
  const TIn* W; const TIn* bi; TIn* C;
  if (blockIdx.z == 0)      { W = Wq; bi = bq; C = Qb; }
  else if (blockIdx.z == 1) { W = Wk; bi = bk; C = Kb; }
  else                      { W = Wv; bi = bv; C = Vb; }
  gemm_core<TIn, false>(x, W, bi, C);
}

// One block per position: 16x16 head-scores, softmax over k-head, 16x64 mix.
// Reads rows pos of Q,K,V; writes attention output IN-PLACE into Qb row pos
// in natural (h*64+d) layout. No cross-block sharing -> in-place is safe.
template <typename TIn, int WANT>
__global__ __launch_bounds__(256) void attn_kernel(const int* __restrict__ flag,
                                                   char* __restrict__ wsb) {
  if (*flag != WANT) return;
  TIn* Qb = (TIn*)wsb;
  const TIn* Kb = (const TIn*)(Qb + MATEL);
  const TIn* Vb = Kb + MATEL;
  const int pos = blockIdx.x;  // n*S + s
  __shared__ float q[Edim], k[Edim], v[Edim];
  __shared__ float p[16][16];
  const int t = threadIdx.x;
  TIn* Qr = Qb + (size_t)pos * Edim;
  const TIn* Kr = Kb + (size_t)pos * Edim;
  const TIn* Vr = Vb + (size_t)pos * Edim;
  for (int i = t; i < Edim; i += 256) {
    q[i] = (float)Qr[i];
    k[i] = (float)Kr[i];
    v[i] = (float)Vr[i];
  }
  __syncthreads();
  {
    const int qh = t >> 4, kh = t & 15;
    float a = 0.f;
#pragma unroll
    for (int d = 0; d < 64; d++) a += q[qh * 64 + d] * k[kh * 64 + d];
    p[qh][kh] = a * 0.125f;  // 1/sqrt(64)
  }
  __syncthreads();
  if (t < 16) {
    float m = -1e30f;
#pragma unroll
    for (int kh = 0; kh < 16; kh++) m = fmaxf(m, p[t][kh]);
    float e[16], sum = 0.f;
#pragma unroll
    for (int kh = 0; kh < 16; kh++) { e[kh] = __expf(p[t][kh] - m); sum += e[kh]; }
    const float inv = 1.f / sum;
#pragma unroll
    for (int kh = 0; kh < 16; kh++) p[t][kh] = e[kh] * inv;
  }
  __syncthreads();
  for (int o = t; o < Edim; o += 256) {
    const int h = o >> 6, d = o & 63;
    float a = 0.f;
#pragma unroll
    for (int l = 0; l < 16; l++) a += p[h][l] * v[l * 64 + d];
    Qr[o] = (TIn)a;  // natural layout: col h*64+d
  }
}

template <typename TIn, int WANT>
__global__ __launch_bounds__(256) void outp_kernel(
    const int* __restrict__ flag, const TIn* __restrict__ Wo,
    const TIn* __restrict__ bo, char* __restrict__ wsb, TIn* __restrict__ out) {
  if (*flag != WANT) return;
  const TIn* Ab = (const TIn*)wsb;  // natural-layout attn output (in Qb)
  gemm_core<TIn, true>(Ab, Wo, bo, out);
}

// ---------------- launcher ----------------
extern "C" void kernel_launch(void* const* d_in, const int* in_sizes, int n_in,
                              void* d_out, int out_size, void* d_ws, size_t ws_size,
                              hipStream_t stream) {
  char* base = (char*)d_ws;
  int* flag = (int*)base;
  char* wsb = base + 256;  // buffers: Q,K,V each MATEL elems of active dtype

  const dim3 blk(256);
  const dim3 gqkv(Mrows / BM, Edim / BN, 3);
  const dim3 gout(Mrows / BM, Edim / BN);

  detect_dtype_kernel<<<1, blk, 0, stream>>>((const unsigned short*)d_in[0], flag);

  // bf16 variant (flag==1)
  qkv_kernel<bf16_t, 1><<<gqkv, blk, 0, stream>>>(
      flag, (const bf16_t*)d_in[0], (const bf16_t*)d_in[1], (const bf16_t*)d_in[2],
      (const bf16_t*)d_in[3], (const bf16_t*)d_in[4], (const bf16_t*)d_in[5],
      (const bf16_t*)d_in[6], wsb);
  // fp32 variant (flag==0)
  qkv_kernel<float, 0><<<gqkv, blk, 0, stream>>>(
      flag, (const float*)d_in[0], (const float*)d_in[1], (const float*)d_in[2],
      (const float*)d_in[3], (const float*)d_in[4], (const float*)d_in[5],
      (const float*)d_in[6], wsb);

  attn_kernel<bf16_t, 1><<<dim3(Mrows), blk, 0, stream>>>(flag, wsb);
  attn_kernel<float, 0><<<dim3(Mrows), blk, 0, stream>>>(flag, wsb);

  outp_kernel<bf16_t, 1><<<gout, blk, 0, stream>>>(
      flag, (const bf16_t*)d_in[7], (const bf16_t*)d_in[8], wsb, (bf16_t*)d_out);
  outp_kernel<float, 0><<<gout, blk, 0, stream>>>(
      flag, (const float*)d_in[7], (const float*)d_in[8], wsb, (float*)d_out);
}

// Round 3
// 388.539 us; speedup vs baseline: 1.9246x; 1.9246x over previous
//
#include <hip/hip_runtime.h>
#include <hip/hip_fp16.h>
#include <stddef.h>

// Problem: N=4, S=4096, E=1024, H=16, D=64. Inputs/outputs fp32 (confirmed
// round 2: LDS_Block_Size=32768 => fp32 variant did the work).
// Reference = "attention over heads": per (n,s) position, 16x16 softmax across
// heads, then scrambled (N,H,S,D)->(N,S,E) reshape + output projection.
// Pipeline (all compute in f16 MFMA + fp32 accumulate; f16 has 2^-11 mantissa
// so single-pass MFMA keeps absmax ~1e-3 vs the 4.09e-2 threshold):
//   K0: convert x, Wq..Wo fp32 -> f16 in ws
//   K1: QKV projections (3x GEMM 16384x1024x1024 NT +bias) -> ws f16
//   K2: per-position head-attention (padded LDS, conflict-free) in-place on Qb
//   K3: output projection, scrambled reshape folded into A staging, fp32 out

typedef _Float16 f16_t;
typedef _Float16 f16x8 __attribute__((ext_vector_type(8)));
typedef _Float16 f16x4 __attribute__((ext_vector_type(4)));
typedef float    f32x4 __attribute__((ext_vector_type(4)));

static constexpr int Sdim = 4096;
static constexpr int Edim = 1024;
static constexpr int Mrows = 4 * Sdim;                  // 16384
static constexpr size_t MATEL = (size_t)Mrows * Edim;   // 16.7M
static constexpr size_t WEL = (size_t)Edim * Edim;      // 1.05M
static constexpr int BM = 128, BN = 128, BK = 32;
static constexpr int TILE = BM * BK;                    // 4096 f16 = 8KB

__device__ __forceinline__ void gload_lds16(const f16_t* g, f16_t* l) {
  // async global->LDS, 16B/lane; LDS dest = wave-uniform base + lane*16 (m97)
  __builtin_amdgcn_global_load_lds(
      (const __attribute__((address_space(1))) void*)g,
      (__attribute__((address_space(3))) void*)l, 16, 0, 0);
}

// ---------------- fp32 -> f16 convert ----------------
__global__ __launch_bounds__(256) void cvt_kernel(
    const float* __restrict__ s0, const float* __restrict__ s1,
    const float* __restrict__ s2, const float* __restrict__ s3,
    const float* __restrict__ s4,
    f16_t* __restrict__ d0, f16_t* __restrict__ d1, f16_t* __restrict__ d2,
    f16_t* __restrict__ d3, f16_t* __restrict__ d4) {
  const float* s; f16_t* d; size_t nv;  // nv = count of float4 groups
  switch (blockIdx.y) {
    case 0: s = s0; d = d0; nv = MATEL / 4; break;
    case 1: s = s1; d = d1; nv = WEL / 4; break;
    case 2: s = s2; d = d2; nv = WEL / 4; break;
    case 3: s = s3; d = d3; nv = WEL / 4; break;
    default: s = s4; d = d4; nv = WEL / 4; break;
  }
  const size_t stride = (size_t)gridDim.x * 256;
  for (size_t i = blockIdx.x * 256 + threadIdx.x; i < nv; i += stride) {
    const f32x4 v = ((const f32x4*)s)[i];
    f16x4 h;
#pragma unroll
    for (int j = 0; j < 4; j++) h[j] = (f16_t)v[j];
    ((f16x4*)d)[i] = h;
  }
}

// ---------------- GEMM core (f16 MFMA, NT, +fp32 bias) ----------------
// C[m,n] = sum_k A[m,k]*B[n,k] + bias[n].  SCRA: A is attn output in NATURAL
// (pos, h*64+d) layout, addressed through the scrambled reshape:
//   scrambled row R = n*4096 + h*256 + s_hi, col c = s_lo*64 + d
//   -> natural row n*4096 + s_hi*16 + s_lo, col h*64 + d
template <bool SCRA, typename TOut>
__device__ __forceinline__ void gemm_f16(const f16_t* __restrict__ A,
                                         const f16_t* __restrict__ B,
                                         const float* __restrict__ bias,
                                         TOut* __restrict__ C) {
  __shared__ __align__(16) f16_t As[TILE];
  __shared__ __align__(16) f16_t Bs[TILE];
  const int t = threadIdx.x;
  const int bm = blockIdx.x * BM;
  const int bn = blockIdx.y * BN;
  const int lane = t & 63;
  const int wave = t >> 6;
  const int wm = (wave >> 1) * 64;  // 2x2 waves of 64x64
  const int wn = (wave & 1) * 64;
  const int row16 = lane & 15;
  const int quad = lane >> 4;

  f32x4 acc[4][4] = {};

  // staging: thread t covers LDS f16[ t*8 .. t*8+8 ) == row t>>2, col (t&3)*8
  const int lr = t >> 2;
  const int lc = (t & 3) * 8;
  f16_t* la = &As[t * 8];
  f16_t* lb = &Bs[t * 8];
  const f16_t* gb = B + (size_t)(bn + lr) * Edim + lc;

  for (int k0 = 0; k0 < Edim; k0 += BK) {
#pragma unroll
    for (int half = 0; half < 2; half++) {
      const f16_t* ga;
      if constexpr (SCRA) {
        const int R = bm + lr + half * 64;
        const int n = R >> 12, h = (R >> 8) & 15, shi = R & 255;
        const int c = k0 + lc;  // 8-elem chunk stays inside one 64-col block
        ga = A + ((size_t)((n << 12) + (shi << 4) + (c >> 6))) * Edim +
             (h << 6) + (c & 63);
      } else {
        ga = A + (size_t)(bm + lr + half * 64) * Edim + k0 + lc;
      }
      gload_lds16(ga, la + half * (64 * BK));
      gload_lds16(gb + k0 + half * (size_t)(64 * Edim), lb + half * (64 * BK));
    }
    __syncthreads();  // drains vmcnt before barrier

    f16x8 af[4], bf[4];
#pragma unroll
    for (int i = 0; i < 4; i++)
      af[i] = *(const f16x8*)&As[(wm + i * 16 + row16) * BK + quad * 8];
#pragma unroll
    for (int j = 0; j < 4; j++)
      bf[j] = *(const f16x8*)&Bs[(wn + j * 16 + row16) * BK + quad * 8];
#pragma unroll
    for (int i = 0; i < 4; i++)
#pragma unroll
      for (int j = 0; j < 4; j++)
        acc[i][j] = __builtin_amdgcn_mfma_f32_16x16x32_f16(af[i], bf[j], acc[i][j], 0, 0, 0);
    __syncthreads();
  }

  // Epilogue. C/D layout: col = lane&15, row = quad*4 + reg  [m89-verified]
#pragma unroll
  for (int j = 0; j < 4; j++) {
    const int col = bn + wn + j * 16 + row16;
    const float bv = bias[col];
#pragma unroll
    for (int i = 0; i < 4; i++) {
      const int rb = bm + wm + i * 16 + quad * 4;
#pragma unroll
      for (int r = 0; r < 4; r++)
        C[(size_t)(rb + r) * Edim + col] = (TOut)(acc[i][j][r] + bv);
    }
  }
}

__global__ __launch_bounds__(256) void qkv_kernel(
    const f16_t* __restrict__ x,
    const f16_t* __restrict__ Wq, const float* __restrict__ bq,
    const f16_t* __restrict__ Wk, const float* __restrict__ bk,
    const f16_t* __restrict__ Wv, const float* __restrict__ bv,
    f16_t* __restrict__ Qb, f16_t* __restrict__ Kb, f16_t* __restrict__ Vb) {
  const f16_t* W; const float* bi; f16_t* C;
  if (blockIdx.z == 0)      { W = Wq; bi = bq; C = Qb; }
  else if (blockIdx.z == 1) { W = Wk; bi = bk; C = Kb; }
  else                      { W = Wv; bi = bv; C = Vb; }
  gemm_f16<false, f16_t>(x, W, bi, C);
}

__global__ __launch_bounds__(256) void outp_kernel(
    const f16_t* __restrict__ Ab, const f16_t* __restrict__ Wo,
    const float* __restrict__ bo, float* __restrict__ out) {
  gemm_f16<true, float>(Ab, Wo, bo, out);
}

// ---------------- per-position head-attention ----------------
// One 256-thread block per (n,s) position. Padded LDS (stride 65) makes the
// 16-deep / 64-deep loops conflict-free (broadcast across 4-lane groups).
// Writes in-place into Qb row pos (natural h*64+d layout) -- race-free.
__global__ __launch_bounds__(256) void attn_kernel(f16_t* __restrict__ Qb,
                                                   const f16_t* __restrict__ Kb,
                                                   const f16_t* __restrict__ Vb) {
  const int pos = blockIdx.x;  // n*S + s
  __shared__ float q[16][65], k[16][65], v[16][65];
  __shared__ float p[16][17];
  const int t = threadIdx.x;
  f16_t* Qr = Qb + (size_t)pos * Edim;
  const f16_t* Kr = Kb + (size_t)pos * Edim;
  const f16_t* Vr = Vb + (size_t)pos * Edim;

  {  // load 4 halves per array per thread (8B, coalesced)
    const int h = t >> 4, d0 = (t & 15) * 4;  // h*64+d0 == 4t
    const f16x4 qq = *(const f16x4*)(Qr + 4 * t);
    const f16x4 kk = *(const f16x4*)(Kr + 4 * t);
    const f16x4 vv = *(const f16x4*)(Vr + 4 * t);
#pragma unroll
    for (int j = 0; j < 4; j++) {
      q[h][d0 + j] = (float)qq[j];
      k[h][d0 + j] = (float)kk[j];
      v[h][d0 + j] = (float)vv[j];
    }
  }
  __syncthreads();
  {  // 16x16 scores: thread t -> (qh, kh)
    const int qh = t >> 4, kh = t & 15;
    float a = 0.f;
#pragma unroll
    for (int d = 0; d < 64; d++) a += q[qh][d] * k[kh][d];
    p[qh][kh] = a * 0.125f;  // 1/sqrt(64)
  }
  __syncthreads();
  if (t < 16) {  // softmax over kh for row t
    float m = -1e30f;
#pragma unroll
    for (int kh = 0; kh < 16; kh++) m = fmaxf(m, p[t][kh]);
    float e[16], sum = 0.f;
#pragma unroll
    for (int kh = 0; kh < 16; kh++) { e[kh] = __expf(p[t][kh] - m); sum += e[kh]; }
    const float inv = 1.f / sum;
#pragma unroll
    for (int kh = 0; kh < 16; kh++) p[t][kh] = e[kh] * inv;
  }
  __syncthreads();
  {  // mix: 4 outputs per thread
    const int h = t >> 4, d0 = (t & 15) * 4;
    float o0 = 0.f, o1 = 0.f, o2 = 0.f, o3 = 0.f;
#pragma unroll
    for (int l = 0; l < 16; l++) {
      const float w = p[h][l];
      o0 += w * v[l][d0];
      o1 += w * v[l][d0 + 1];
      o2 += w * v[l][d0 + 2];
      o3 += w * v[l][d0 + 3];
    }
    f16x4 r;
    r[0] = (f16_t)o0; r[1] = (f16_t)o1; r[2] = (f16_t)o2; r[3] = (f16_t)o3;
    *(f16x4*)(Qr + 4 * t) = r;
  }
}

// ---------------- launcher ----------------
extern "C" void kernel_launch(void* const* d_in, const int* in_sizes, int n_in,
                              void* d_out, int out_size, void* d_ws, size_t ws_size,
                              hipStream_t stream) {
  const float* x  = (const float*)d_in[0];
  const float* Wq = (const float*)d_in[1];
  const float* bq = (const float*)d_in[2];
  const float* Wk = (const float*)d_in[3];
  const float* bk = (const float*)d_in[4];
  const float* Wv = (const float*)d_in[5];
  const float* bv = (const float*)d_in[6];
  const float* Wo = (const float*)d_in[7];
  const float* bo = (const float*)d_in[8];
  float* out = (float*)d_out;

  f16_t* xh  = (f16_t*)d_ws;          // 33.5 MB
  f16_t* Wqh = xh + MATEL;            // 2 MB each
  f16_t* Wkh = Wqh + WEL;
  f16_t* Wvh = Wkh + WEL;
  f16_t* Woh = Wvh + WEL;
  f16_t* Qb  = Woh + WEL;             // 33.5 MB each
  f16_t* Kb  = Qb + MATEL;
  f16_t* Vb  = Kb + MATEL;            // total ~143 MB (round-2 used 201 MB OK)

  const dim3 blk(256);
  cvt_kernel<<<dim3(2048, 5), blk, 0, stream>>>(x, Wq, Wk, Wv, Wo,
                                                xh, Wqh, Wkh, Wvh, Woh);
  qkv_kernel<<<dim3(Mrows / BM, Edim / BN, 3), blk, 0, stream>>>(
      xh, Wqh, bq, Wkh, bk, Wvh, bv, Qb, Kb, Vb);
  attn_kernel<<<dim3(Mrows), blk, 0, stream>>>(Qb, Kb, Vb);
  outp_kernel<<<dim3(Mrows / BM, Edim / BN), blk, 0, stream>>>(Qb, Woh, bo, out);
}